// Round 1
// baseline (180.947 us; speedup 1.0000x reference)
//
#include <hip/hip_runtime.h>
#include <hip/hip_bf16.h>

#define Bb 32
#define Ss 2048
#define Kk 1024   // 2*EH = 2*DH
#define Aa 512

#define BM 128
#define BK 64
#define LDSA (BM * BK * 2)   // 16 KB
#define LDSB (Aa * BK * 2)   // 64 KB

typedef __bf16 bf16x8 __attribute__((ext_vector_type(8)));
typedef float f32x4 __attribute__((ext_vector_type(4)));

__device__ __forceinline__ unsigned short f2bf(float f) {
  unsigned u = __float_as_uint(f);
  u += 0x7FFFu + ((u >> 16) & 1u);   // RNE
  return (unsigned short)(u >> 16);
}

__device__ __forceinline__ float tanh_fast(float x) {
  float e = __expf(2.f * x);
  return (e - 1.f) / (e + 1.f);
}

// ---- prep: Wt[a][k] = bf16(W[k][a]) ----
__global__ __launch_bounds__(256) void prep_wt(const float* __restrict__ W,
                                               unsigned short* __restrict__ Wt) {
  int idx = blockIdx.x * 256 + threadIdx.x;   // 524288 total
  int a = idx & (Aa - 1);
  int k = idx >> 9;
  Wt[a * Kk + k] = f2bf(W[(size_t)k * Aa + a]);
}

// ---- temp2 = [dh0|dh1] @ U, chunked over k ----
__global__ __launch_bounds__(256) void t2_partial(const float* __restrict__ dh,
                                                  const float* __restrict__ U,
                                                  float* __restrict__ part) {
  const int b = blockIdx.x, kc = blockIdx.y, t = threadIdx.x;  // (32, 8)
  __shared__ float sdh[128];
  if (t < 128) {
    int k = kc * 128 + t;
    sdh[t] = dh[(k >> 9) * (Bb * 512) + b * 512 + (k & 511)];
  }
  __syncthreads();
#pragma unroll
  for (int h = 0; h < 2; ++h) {
    const int a = h * 256 + t;
    float s = 0.f;
#pragma unroll 8
    for (int kk = 0; kk < 128; ++kk) s += sdh[kk] * U[(size_t)(kc * 128 + kk) * Aa + a];
    part[(size_t)(b * 8 + kc) * Aa + a] = s;
  }
}

__global__ __launch_bounds__(256) void t2_reduce(const float* __restrict__ part,
                                                 float* __restrict__ t2) {
  const int idx = blockIdx.x * 256 + threadIdx.x;  // 16384
  const int b = idx >> 9, a = idx & 511;
  float s = 0.f;
#pragma unroll
  for (int kc = 0; kc < 8; ++kc) s += part[(size_t)(b * 8 + kc) * Aa + a];
  t2[idx] = s;
}

// ---- main: scores = tanh(enc@W + t2) @ v  (bf16 MFMA, fused epilogue) ----
__global__ __launch_bounds__(512) void score_gemm(const float* __restrict__ enc,
                                                  const unsigned short* __restrict__ Wt,
                                                  const float* __restrict__ t2,
                                                  const float* __restrict__ v,
                                                  float* __restrict__ score) {
  __shared__ __align__(16) char lds[LDSA + LDSB];   // 80 KB
  char* sA = lds;
  char* sB = lds + LDSA;

  const int blk = blockIdx.x;               // 512 blocks
  const int b = blk >> 4, sc = blk & 15;
  const float* encBase = enc + (size_t)(b * Ss + sc * BM) * Kk;

  const int tid = threadIdx.x;
  const int lane = tid & 63;
  const int wid = tid >> 6;
  const int wy = wid >> 2, wx = wid & 3;    // 2 x 4 wave grid, wave tile 64x128

  const f32x4 zero = {0.f, 0.f, 0.f, 0.f};
  f32x4 acc[4][8];
#pragma unroll
  for (int i = 0; i < 4; ++i)
#pragma unroll
    for (int j = 0; j < 8; ++j) acc[i][j] = zero;

  for (int t = 0; t < Kk / BK; ++t) {
    const int k0 = t * BK;
    // stage A tile: 128x64 fp32 -> bf16, swizzled
#pragma unroll
    for (int p = 0; p < 4; ++p) {
      int f = tid + p * 512;
      int r = f >> 4;
      int c4 = (f & 15) << 2;
      const float4 src = *(const float4*)(encBase + r * Kk + k0 + c4);
      ushort4 w;
      w.x = f2bf(src.x); w.y = f2bf(src.y); w.z = f2bf(src.z); w.w = f2bf(src.w);
      int byteoff = r * (BK * 2) + ((c4 * 2) ^ ((r & 7) << 4));
      *(ushort4*)(sA + byteoff) = w;
    }
    // stage B tile: 512x64 bf16 (already converted), swizzled
#pragma unroll
    for (int q = 0; q < 8; ++q) {
      int f = tid + q * 512;
      int a = f >> 3;
      int c8 = (f & 7) << 3;
      const uint4 src = *(const uint4*)(Wt + (size_t)a * Kk + k0 + c8);
      int byteoff = a * (BK * 2) + ((c8 * 2) ^ ((a & 7) << 4));
      *(uint4*)(sB + byteoff) = src;
    }
    __syncthreads();
#pragma unroll
    for (int kk = 0; kk < 2; ++kk) {
      bf16x8 af[4], bfr[8];
      const int kb = (kk * 32 + ((lane >> 4) << 3)) * 2;
#pragma unroll
      for (int mi = 0; mi < 4; ++mi) {
        int r = wy * 64 + mi * 16 + (lane & 15);
        af[mi] = *(const bf16x8*)(sA + r * (BK * 2) + (kb ^ ((r & 7) << 4)));
      }
#pragma unroll
      for (int ni = 0; ni < 8; ++ni) {
        int a = wx * 128 + ni * 16 + (lane & 15);
        bfr[ni] = *(const bf16x8*)(sB + a * (BK * 2) + (kb ^ ((a & 7) << 4)));
      }
#pragma unroll
      for (int mi = 0; mi < 4; ++mi)
#pragma unroll
        for (int ni = 0; ni < 8; ++ni)
          acc[mi][ni] = __builtin_amdgcn_mfma_f32_16x16x32_bf16(af[mi], bfr[ni], acc[mi][ni], 0, 0, 0);
    }
    __syncthreads();
  }

  // epilogue: score_row += tanh(acc + t2[col]) * v[col], reduced over 512 cols
  float t2v[8], vv[8];
#pragma unroll
  for (int ni = 0; ni < 8; ++ni) {
    int c = wx * 128 + ni * 16 + (lane & 15);
    t2v[ni] = t2[b * Aa + c];
    vv[ni] = v[c];
  }
  float sp[4][4];
#pragma unroll
  for (int mi = 0; mi < 4; ++mi)
#pragma unroll
    for (int j = 0; j < 4; ++j) sp[mi][j] = 0.f;
#pragma unroll
  for (int mi = 0; mi < 4; ++mi)
#pragma unroll
    for (int ni = 0; ni < 8; ++ni)
#pragma unroll
      for (int j = 0; j < 4; ++j) {
        float x = acc[mi][ni][j] + t2v[ni];
        sp[mi][j] += vv[ni] * tanh_fast(x);
      }

  // C/D layout: col = lane&15, row = (lane>>4)*4 + j. Reduce over the 16 col-lanes.
  float* sbuf = (float*)lds;   // [128][4], safe: last loop iter ended with syncthreads
#pragma unroll
  for (int mi = 0; mi < 4; ++mi)
#pragma unroll
    for (int j = 0; j < 4; ++j) {
      float s = sp[mi][j];
      s += __shfl_xor(s, 1);
      s += __shfl_xor(s, 2);
      s += __shfl_xor(s, 4);
      s += __shfl_xor(s, 8);
      if ((lane & 15) == 0) {
        int r = wy * 64 + mi * 16 + ((lane >> 4) << 2) + j;
        sbuf[r * 4 + wx] = s;
      }
    }
  __syncthreads();
  if (tid < BM) {
    float s = sbuf[tid * 4] + sbuf[tid * 4 + 1] + sbuf[tid * 4 + 2] + sbuf[tid * 4 + 3];
    score[b * Ss + sc * BM + tid] = s;
  }
}

// ---- softmax over S, in place in d_out's attention region ----
__global__ __launch_bounds__(256) void softmax_k(float* __restrict__ aw) {
  const int b = blockIdx.x, t = threadIdx.x;
  __shared__ float red[8];
  float s[8];
  float m = -3.4e38f;
#pragma unroll
  for (int i = 0; i < 8; ++i) {
    s[i] = aw[b * Ss + t + i * 256];
    m = fmaxf(m, s[i]);
  }
#pragma unroll
  for (int off = 1; off < 64; off <<= 1) m = fmaxf(m, __shfl_xor(m, off));
  const int lane = t & 63, wv = t >> 6;
  if (lane == 0) red[wv] = m;
  __syncthreads();
  m = fmaxf(fmaxf(red[0], red[1]), fmaxf(red[2], red[3]));
  float e[8];
  float l = 0.f;
#pragma unroll
  for (int i = 0; i < 8; ++i) { e[i] = __expf(s[i] - m); l += e[i]; }
#pragma unroll
  for (int off = 1; off < 64; off <<= 1) l += __shfl_xor(l, off);
  if (lane == 0) red[4 + wv] = l;
  __syncthreads();
  l = red[4] + red[5] + red[6] + red[7];
  const float inv = 1.f / l;
#pragma unroll
  for (int i = 0; i < 8; ++i) aw[b * Ss + t + i * 256] = e[i] * inv;
}

// ---- context = sum_s aw[s] * enc[b,s,:], chunked partials + reduce ----
__global__ __launch_bounds__(256) void ctx_partial(const float* __restrict__ enc,
                                                   const float* __restrict__ aw,
                                                   float* __restrict__ part) {
  const int b = blockIdx.x, ch = blockIdx.y, t = threadIdx.x;  // (32, 32)
  __shared__ float sw[64];
  const int s0 = ch * 64;
  if (t < 64) sw[t] = aw[b * Ss + s0 + t];
  __syncthreads();
  float ax = 0.f, ay = 0.f, az = 0.f, aww = 0.f;
  const float* ebase = enc + (size_t)(b * Ss + s0) * Kk + t * 4;
#pragma unroll 4
  for (int r = 0; r < 64; ++r) {
    const float4 ev = *(const float4*)(ebase + (size_t)r * Kk);
    const float w = sw[r];
    ax += w * ev.x; ay += w * ev.y; az += w * ev.z; aww += w * ev.w;
  }
  float4 o; o.x = ax; o.y = ay; o.z = az; o.w = aww;
  *(float4*)(part + (size_t)(b * 32 + ch) * Kk + t * 4) = o;
}

__global__ __launch_bounds__(256) void ctx_reduce(const float* __restrict__ part,
                                                  float* __restrict__ ctx) {
  const int idx = blockIdx.x * 256 + threadIdx.x;   // 32768
  const int b = idx >> 10, e = idx & 1023;
  float s = 0.f;
#pragma unroll
  for (int ch = 0; ch < 32; ++ch) s += part[(size_t)(b * 32 + ch) * Kk + e];
  ctx[idx] = s;
}

extern "C" void kernel_launch(void* const* d_in, const int* in_sizes, int n_in,
                              void* d_out, int out_size, void* d_ws, size_t ws_size,
                              hipStream_t stream) {
  const float* dh  = (const float*)d_in[0];   // (2, 32, 512)
  const float* enc = (const float*)d_in[1];   // (32, 2048, 1024)
  const float* W   = (const float*)d_in[2];   // (1024, 512)
  const float* U   = (const float*)d_in[3];   // (1024, 512)
  const float* v   = (const float*)d_in[4];   // (512, 1)

  float* out_ctx = (float*)d_out;             // (32, 1, 1024) = 32768
  float* out_aw  = (float*)d_out + 32768;     // (32, 2048)    = 65536

  char* ws = (char*)d_ws;
  unsigned short* Wt = (unsigned short*)ws;                 // 1 MB
  float* t2p   = (float*)(ws + 1048576);                    // 512 KB
  float* t2    = (float*)(ws + 1048576 + 524288);           // 64 KB
  float* cpart = (float*)(ws + 1048576 + 524288 + 65536);   // 4 MB

  prep_wt<<<2048, 256, 0, stream>>>(W, Wt);
  t2_partial<<<dim3(32, 8), 256, 0, stream>>>(dh, U, t2p);
  t2_reduce<<<64, 256, 0, stream>>>(t2p, t2);
  // raw scores written straight into the attention-weights output region
  score_gemm<<<512, 512, 0, stream>>>(enc, Wt, t2, v, out_aw);
  softmax_k<<<32, 256, 0, stream>>>(out_aw);
  ctx_partial<<<dim3(32, 32), 256, 0, stream>>>(enc, out_aw, cpart);
  ctx_reduce<<<128, 256, 0, stream>>>(cpart, out_ctx);
}